// Round 14
// baseline (444.407 us; speedup 1.0000x reference)
//
#include <hip/hip_runtime.h>
#include <math.h>

#define NFEAT 128
#define F1    30   // conv1 out features
#define F1P   32   // padded width for conv1 tables
#define F2    20   // conv2 out features

#define EPB   8192   // edges per block in CSR-build passes
#define BW    512    // bucket width (nodes per bucket), key = dst >> 9
#define EDCAP 9216   // LDS staging cap per half-bucket (mean 8192 + 11 sigma)

typedef float vfloat4 __attribute__((ext_vector_type(4)));  // native vec for NT builtins

__device__ __forceinline__ int ntload(const int* p) { return __builtin_nontemporal_load(p); }
__device__ __forceinline__ float ntloadf(const float* p) { return __builtin_nontemporal_load(p); }
__device__ __forceinline__ void ntstore(int* p, int v) { __builtin_nontemporal_store(v, p); }
__device__ __forceinline__ void ntstoref(float* p, float v) { __builtin_nontemporal_store(v, p); }
__device__ __forceinline__ float4 ntload4(const float* p) {
    vfloat4 v = __builtin_nontemporal_load((const vfloat4*)p);
    return make_float4(v.x, v.y, v.z, v.w);
}

// ------- k_p1: per-block bucket histogram; last block preps padded weights -----
__global__ __launch_bounds__(512) void k_p1(
    const int* __restrict__ ei, int* __restrict__ blockCnt, int E, int nbuck,
    const float* __restrict__ Wrel, const float* __restrict__ Wroot,
    float* __restrict__ Wp, int neb)
{
    int t = threadIdx.x;
    if (blockIdx.x == (unsigned)neb) {            // fused k_prepw
        for (int i = t; i < 2 * 128 * 32; i += 512) {
            int table = i >> 12, rem = i & 4095, k = rem >> 5, j = rem & 31;
            const float* W = table ? Wroot : Wrel;
            Wp[i] = (j < F1) ? W[k * F1 + j] : 0.f;
        }
        return;
    }
    __shared__ int lh[256];
    for (int i = t; i < 256; i += 512) lh[i] = 0;
    __syncthreads();
    const int* dst = ei + E;
    int base = blockIdx.x * EPB;
#pragma unroll 4
    for (int k = 0; k < EPB / 512; k++) {
        int e = base + k * 512 + t;
        if (e < E) atomicAdd(&lh[ntload(dst + e) >> 9], 1);
    }
    __syncthreads();
    int* out = blockCnt + (size_t)blockIdx.x * nbuck;
    for (int i = t; i < nbuck; i += 512) out[i] = lh[i];
}

// ------- k_p2: per-bucket exclusive scan across edge-blocks --------------------
__global__ __launch_bounds__(256) void k_p2(
    const int* __restrict__ blockCnt, int* __restrict__ blockOff,
    int* __restrict__ bucketTot, int neb, int nbuck)
{
    __shared__ int sdata[256];
    __shared__ int carry_s;
    int b = blockIdx.x;
    int t = threadIdx.x;
    if (t == 0) carry_s = 0;
    __syncthreads();
    for (int base = 0; base < neb; base += 512) {
        int i0 = base + 2 * t, i1 = i0 + 1;
        int c0 = (i0 < neb) ? blockCnt[(size_t)i0 * nbuck + b] : 0;
        int c1 = (i1 < neb) ? blockCnt[(size_t)i1 * nbuck + b] : 0;
        int s = c0 + c1;
        sdata[t] = s;
        __syncthreads();
        for (int off = 1; off < 256; off <<= 1) {
            int tmp = (t >= off) ? sdata[t - off] : 0;
            __syncthreads();
            sdata[t] += tmp;
            __syncthreads();
        }
        int ex = carry_s + sdata[t] - s;
        if (i0 < neb) blockOff[(size_t)i0 * nbuck + b] = ex;
        if (i1 < neb) blockOff[(size_t)i1 * nbuck + b] = ex + c0;
        __syncthreads();
        if (t == 255) carry_s += sdata[255];
        __syncthreads();
    }
    if (t == 0) bucketTot[b] = carry_s;
}

// ------- k_p4: folds p3 (per-block scan of bucketTot) + bucket scatter ---------
__global__ __launch_bounds__(512) void k_p4(
    const int* __restrict__ ei, const int* __restrict__ bucketTot,
    const int* __restrict__ blockOff, int* __restrict__ ebuf,
    int* __restrict__ gBucketStart, int E, int nbuck)
{
    __shared__ int sV[256];       // bucketTot values
    __shared__ int sS[256];       // inclusive scan
    __shared__ int cur[256];
    int t = threadIdx.x;
    if (t < 256) {
        int v = (t < nbuck) ? bucketTot[t] : 0;
        sV[t] = v;
        sS[t] = v;
    }
    __syncthreads();
    for (int off = 1; off < 256; off <<= 1) {
        int tmp = 0;
        if (t < 256 && t >= off) tmp = sS[t - off];
        __syncthreads();
        if (t < 256) sS[t] += tmp;
        __syncthreads();
    }
    // bucketStart[i] = incl[i] - v[i]  (exclusive)
    const int* boff = blockOff + (size_t)blockIdx.x * nbuck;
    if (t < 256) {
        int bs = sS[t] - sV[t];
        cur[t] = (t < nbuck) ? bs + boff[t] : 0;
        if (blockIdx.x == 0) {                    // publish for k_p6
            if (t < nbuck) gBucketStart[t] = bs;
            if (t == 0) gBucketStart[nbuck] = sS[255];
        }
    }
    __syncthreads();
    const int* dst = ei + E;
    int base = blockIdx.x * EPB;
#pragma unroll 4
    for (int k = 0; k < EPB / 512; k++) {
        int e = base + k * 512 + t;
        if (e < E) {
            int s = ntload(ei + e), d = ntload(dst + e);
            int p = atomicAdd(&cur[d >> 9], 1);
            ntstore(ebuf + p, (s << 9) | (d & 511));
        }
    }
}

// p6: per-HALF-bucket LDS counting sort -> perm (sequential write) + deg/rowstart
__global__ __launch_bounds__(512) void k_p6(
    const int* __restrict__ ebuf, const int* __restrict__ bucketStart,
    int* __restrict__ perm, int* __restrict__ deg, int* __restrict__ rowstart,
    int n, int t1, int t2, int t3)
{
    __shared__ int ed2[EDCAP];            // 36 KB staging
    __shared__ int hist[1024];            // (node-in-half, quartile) bins
    __shared__ int sdata[512];
    __shared__ int m0_s;
    int t = threadIdx.x;
    int b = blockIdx.x >> 1;
    int h = blockIdx.x & 1;
    int lo = bucketStart[b], hi = bucketStart[b + 1];
    hist[t] = 0; hist[t + 512] = 0;
    if (t == 0) m0_s = 0;
    __syncthreads();

    int c0 = 0;
    for (int p = lo + t; p < hi; p += 512) {
        int e = ntload(ebuf + p);
        int dl9 = e & 511;
        if ((dl9 >> 8) == 0) c0++;
        if ((dl9 >> 8) == h) {
            int src = e >> 9;
            int qq = (src >= t1) + (src >= t2) + (src >= t3);
            atomicAdd(&hist[(dl9 & 255) * 4 + qq], 1);
        }
    }
    atomicAdd(&m0_s, c0);
    __syncthreads();

    int v0 = hist[2 * t], v1 = hist[2 * t + 1];
    int ps = v0 + v1;
    sdata[t] = ps;
    __syncthreads();
    for (int off = 1; off < 512; off <<= 1) {
        int tmp = (t >= off) ? sdata[t - off] : 0;
        __syncthreads();
        sdata[t] += tmp;
        __syncthreads();
    }
    int ex = sdata[t] - ps;
    hist[2 * t] = ex;
    hist[2 * t + 1] = ex + v0;
    __syncthreads();
    int mh = sdata[511];
    int base = lo + (h ? m0_s : 0);

    if (t < 256) {
        int node = b * BW + h * 256 + t;
        if (node < n) {
            int s0 = hist[t * 4];
            int s1 = (t == 255) ? mh : hist[(t + 1) * 4];
            deg[node] = s1 - s0;
            rowstart[node] = base + s0;
        }
    }
    __syncthreads();

    for (int p = lo + t; p < hi; p += 512) {
        int e = ntload(ebuf + p);
        int dl9 = e & 511;
        if ((dl9 >> 8) == h) {
            int src = e >> 9;
            int qq = (src >= t1) + (src >= t2) + (src >= t3);
            int pos = atomicAdd(&hist[(dl9 & 255) * 4 + qq], 1);
            if (pos < EDCAP) ed2[pos] = src;
            else perm[base + pos] = src;
        }
    }
    __syncthreads();

    int mw = min(mh, EDCAP);
    for (int i = t; i < mw; i += 512) ntstore(perm + base + i, ed2[i]);
}

// ------- k_proj1: block=512 (8 waves), 64 nodes/block. wave=(table,q) uniform ---
__global__ __launch_bounds__(512) void k_proj1(
    const float* __restrict__ x, const float* __restrict__ Wp,
    float* __restrict__ y1, float* __restrict__ r1, int n)
{
    __shared__ float4 xs4[2048];           // 64 rows x 32 k4, swizzled, 32 KB
    int tid = threadIdx.x;
    int base = blockIdx.x * 64;

#pragma unroll
    for (int it = 0; it < 4; it++) {
        int idx = it * 512 + tid;
        int k4 = idx & 31, row = idx >> 5;
        int gnode = base + row;
        float4 v = make_float4(0.f, 0.f, 0.f, 0.f);
        if (gnode < n) v = ntload4(x + (size_t)gnode * NFEAT + k4 * 4);
        xs4[k4 * 64 + (row ^ k4)] = v;
    }
    __syncthreads();

    int lane = tid & 63;
    int combo = __builtin_amdgcn_readfirstlane(tid >> 6);  // 0..7, wave-uniform
    int table = combo >> 2, q = combo & 3;
    int node = base + lane;
    if (node >= n) return;

    const float* Wt = Wp + table * 4096 + q * 8;           // SGPR-derived
    float acc[8];
#pragma unroll
    for (int j = 0; j < 8; j++) acc[j] = 0.f;

    for (int k4 = 0; k4 < 32; k4++) {
        float4 xk = xs4[k4 * 64 + (lane ^ k4)];
#pragma unroll
        for (int kk = 0; kk < 4; kk++) {
            float xs = kk == 0 ? xk.x : kk == 1 ? xk.y : kk == 2 ? xk.z : xk.w;
            const float* w = Wt + (k4 * 4 + kk) * 32;      // wave-uniform -> s_load
            acc[0] += xs * w[0]; acc[1] += xs * w[1];
            acc[2] += xs * w[2]; acc[3] += xs * w[3];
            acc[4] += xs * w[4]; acc[5] += xs * w[5];
            acc[6] += xs * w[6]; acc[7] += xs * w[7];
        }
    }
    float* outp = (table ? r1 : y1) + (size_t)node * F1P + q * 8;
    ((float4*)outp)[0] = make_float4(acc[0], acc[1], acc[2], acc[3]);
    ((float4*)outp)[1] = make_float4(acc[4], acc[5], acc[6], acc[7]);
}

// ------- k_agg1m: conv1 gather + bn1 + 30->20x2 matmul fused (32 nodes/block) --
__global__ __launch_bounds__(256) void k_agg1m(
    const int* __restrict__ rowstart, const int* __restrict__ deg,
    const int* __restrict__ perm, const float* __restrict__ y1,
    const float* __restrict__ r1,
    const float* __restrict__ b1, const float* __restrict__ g1,
    const float* __restrict__ bb1, const float* __restrict__ m1,
    const float* __restrict__ v1,
    const float* __restrict__ Wrel2, const float* __restrict__ Wroot2,
    const float* __restrict__ b2,
    float* __restrict__ y2, float* __restrict__ r2, int n)
{
    __shared__ float sAcc[32][33];
    __shared__ float sH[32][31];
    __shared__ float sW[30][40];        // [k][o]: o<20 -> Wrel2, o>=20 -> Wroot2
    __shared__ float sP[4][30];         // b1, sc1, m1, bb1
    __shared__ float sB2[20];
    int t = threadIdx.x;
    int base = blockIdx.x * 32;
    int nl = t >> 3, q = t & 7;
    int node = base + nl;

    if (t < 30) {
        sP[0][t] = b1[t];
        sP[1][t] = g1[t] / sqrtf(v1[t] + 1e-5f);
        sP[2][t] = m1[t];
        sP[3][t] = bb1[t];
    }
    if (t >= 32 && t < 52) sB2[t - 32] = b2[t - 32];
    for (int i = t; i < 1200; i += 256) {
        int k = i / 40, o = i - k * 40;
        sW[k][o] = (o < 20) ? Wrel2[k * 20 + o] : Wroot2[k * 20 + (o - 20)];
    }

    // gather (same order as before -> identical sums); perm reads non-temporal
    float4 acc = {0.f, 0.f, 0.f, 0.f};
    if (node < n) {
        int s = rowstart[node], e = s + deg[node];
        int j = s;
        for (; j + 8 <= e; j += 8) {
            int myp = ntload(perm + j + q);
#pragma unroll
            for (int k = 0; k < 8; k++) {
                int sr = __shfl(myp, k, 8);
                float4 v = *(const float4*)(y1 + (size_t)sr * F1P + q * 4);
                acc.x += v.x; acc.y += v.y; acc.z += v.z; acc.w += v.w;
            }
        }
        for (; j < e; j++) {
            int sr = ntload(perm + j);
            float4 v = *(const float4*)(y1 + (size_t)sr * F1P + q * 4);
            acc.x += v.x; acc.y += v.y; acc.z += v.z; acc.w += v.w;
        }
    }
    sAcc[nl][q * 4 + 0] = acc.x; sAcc[nl][q * 4 + 1] = acc.y;
    sAcc[nl][q * 4 + 2] = acc.z; sAcc[nl][q * 4 + 3] = acc.w;
    __syncthreads();

    // h = bn1(relu(acc + r1 + b1)) over 32x30; r1 reads non-temporal
    for (int w = t; w < 960; w += 256) {
        int wl = w / 30, k = w - wl * 30;
        int nd = base + wl;
        if (nd < n) {
            float a = sAcc[wl][k] + ntloadf(r1 + (size_t)nd * F1P + k) + sP[0][k];
            a = fmaxf(a, 0.f);
            sH[wl][k] = (a - sP[2][k]) * sP[1][k] + sP[3][k];
        }
    }
    __syncthreads();

    // matmul: thread (nl,q) computes 5 outputs; o<20 -> y2, o>=20 -> r2 (+b2)
    if (node < n) {
        int ob = q * 5;
        bool isroot = (ob >= 20);
        float o0 = 0.f, o1 = 0.f, o2 = 0.f, o3 = 0.f, o4 = 0.f;
        if (isroot) {
            o0 = sB2[ob - 20]; o1 = sB2[ob - 19]; o2 = sB2[ob - 18];
            o3 = sB2[ob - 17]; o4 = sB2[ob - 16];
        }
        for (int k = 0; k < 30; k++) {
            float hk = sH[nl][k];
            o0 += hk * sW[k][ob + 0];
            o1 += hk * sW[k][ob + 1];
            o2 += hk * sW[k][ob + 2];
            o3 += hk * sW[k][ob + 3];
            o4 += hk * sW[k][ob + 4];
        }
        float* dst = isroot ? (r2 + (size_t)node * F2 + (ob - 20))
                            : (y2 + (size_t)node * F2 + ob);
        ntstoref(dst + 0, o0); ntstoref(dst + 1, o1); ntstoref(dst + 2, o2);
        ntstoref(dst + 3, o3); ntstoref(dst + 4, o4);
    }
}

// ------- k_agg2p: conv2 gather + bn2 + pool flush fused (32 nodes/block) -------
__global__ __launch_bounds__(256) void k_agg2p(
    const int* __restrict__ rowstart, const int* __restrict__ deg,
    const int* __restrict__ perm, const float* __restrict__ y2,
    const float* __restrict__ r2, const int* __restrict__ batch,
    const float* __restrict__ g2, const float* __restrict__ bb2,
    const float* __restrict__ m2, const float* __restrict__ v2,
    unsigned* __restrict__ gmaxU, float* __restrict__ gsum,
    int* __restrict__ cnt, int n)
{
    __shared__ float sAcc[32][21];
    __shared__ float sH[32][21];
    __shared__ float sSc[20], sM[20], sBb[20];
    __shared__ int   sB[32];
    int t = threadIdx.x;
    int base = blockIdx.x * 32;
    int nl = t >> 3, q = t & 7;
    int node = base + nl;

    if (t < 20) {
        sSc[t] = g2[t] / sqrtf(v2[t] + 1e-5f);
        sM[t]  = m2[t];
    }
    if (t >= 32 && t < 52) sBb[t - 32] = bb2[t - 32];
    if (t >= 64 && t < 96) {
        int nd = base + (t - 64);
        sB[t - 64] = (nd < n) ? batch[nd] : -1;
    }

    bool valid = (q < 5);
    float4 acc = {0.f, 0.f, 0.f, 0.f};
    if (node < n) {
        int s = rowstart[node], e = s + deg[node];
        int j = s;
        for (; j + 8 <= e; j += 8) {
            int myp = ntload(perm + j + q);
#pragma unroll
            for (int k = 0; k < 8; k++) {
                int sr = __shfl(myp, k, 8);
                if (valid) {
                    float4 v = *(const float4*)(y2 + (size_t)sr * F2 + q * 4);
                    acc.x += v.x; acc.y += v.y; acc.z += v.z; acc.w += v.w;
                }
            }
        }
        if (valid) {
            for (; j < e; j++) {
                int sr = ntload(perm + j);
                float4 v = *(const float4*)(y2 + (size_t)sr * F2 + q * 4);
                acc.x += v.x; acc.y += v.y; acc.z += v.z; acc.w += v.w;
            }
        }
    }
    if (valid && node < n) {
        sAcc[nl][q * 4 + 0] = acc.x; sAcc[nl][q * 4 + 1] = acc.y;
        sAcc[nl][q * 4 + 2] = acc.z; sAcc[nl][q * 4 + 3] = acc.w;
    }
    __syncthreads();

    // h2 = bn2(relu(acc + r2)); r2 reads non-temporal (b2 folded into r2)
    for (int w = t; w < 640; w += 256) {
        int wl = w / 20, f = w - wl * 20;
        int nd = base + wl;
        if (nd < n) {
            float a = sAcc[wl][f] + ntloadf(r2 + (size_t)nd * F2 + f);
            a = fmaxf(a, 0.f);
            sH[wl][f] = (a - sM[f]) * sSc[f] + sBb[f];
        }
    }
    __syncthreads();

    // segmented flush (batch sorted): t<20 per-feature sum/max, t==20 counts
    if (t < 20) {
        int f = t;
        int curg = -1; float sm = 0.f, mx = -3.4e38f;
        for (int wl = 0; wl < 32; wl++) {
            int g = sB[wl];
            if (g < 0) break;
            if (g != curg) {
                if (curg >= 0) {
                    atomicAdd(&gsum[curg * F2 + f], sm);
                    unsigned bits = __float_as_uint(mx);
                    unsigned mp = (bits & 0x80000000u) ? ~bits : (bits | 0x80000000u);
                    atomicMax(&gmaxU[curg * F2 + f], mp);
                }
                curg = g; sm = 0.f; mx = -3.4e38f;
            }
            float h2 = sH[wl][f];
            sm += h2; mx = fmaxf(mx, h2);
        }
        if (curg >= 0) {
            atomicAdd(&gsum[curg * F2 + f], sm);
            unsigned bits = __float_as_uint(mx);
            unsigned mp = (bits & 0x80000000u) ? ~bits : (bits | 0x80000000u);
            atomicMax(&gmaxU[curg * F2 + f], mp);
        }
    } else if (t == 20) {
        int curg = -1, c = 0;
        for (int wl = 0; wl < 32; wl++) {
            int g = sB[wl];
            if (g < 0) break;
            if (g != curg) {
                if (curg >= 0) atomicAdd(&cnt[curg], c);
                curg = g; c = 0;
            }
            c++;
        }
        if (curg >= 0) atomicAdd(&cnt[curg], c);
    }
}

// ---------------- Kernel F: head MLP + sigmoid ---------------------------------
__global__ __launch_bounds__(256) void k_head(
    const unsigned* __restrict__ gmaxU, const float* __restrict__ gsum,
    const int* __restrict__ cnt,
    const float* __restrict__ W1, const float* __restrict__ b1h,
    const float* __restrict__ W2, const float* __restrict__ b2h,
    float* __restrict__ out, int G)
{
    int g = blockIdx.x * 256 + threadIdx.x;
    if (g >= G) return;
    int c = cnt[g];
    float cf = fmaxf((float)c, 1.f);
    float z[2 * F2];
#pragma unroll
    for (int j = 0; j < F2; j++) {
        unsigned u = gmaxU[g * F2 + j];
        float gm = 0.f;
        if (c != 0) {
            gm = (u & 0x80000000u) ? __uint_as_float(u & 0x7FFFFFFFu)
                                   : __uint_as_float(~u);
            if (!isfinite(gm)) gm = 0.f;
        }
        z[j]      = gm;
        z[F2 + j] = gsum[g * F2 + j] / cf;
    }
    float a[10];
#pragma unroll
    for (int i = 0; i < 10; i++) a[i] = b1h[i];
    for (int k = 0; k < 2 * F2; k++) {
        float zk = z[k];
#pragma unroll
        for (int i = 0; i < 10; i++) a[i] += zk * W1[k * 10 + i];
    }
    float o = b2h[0];
#pragma unroll
    for (int i = 0; i < 10; i++) o += fmaxf(a[i], 0.f) * W2[i];
    out[g] = 1.f / (1.f + expf(-o));
}

// ---------------- launch (dedicated regions, NO aliasing) -----------------------
extern "C" void kernel_launch(void* const* d_in, const int* in_sizes, int n_in,
                              void* d_out, int out_size, void* d_ws, size_t ws_size,
                              hipStream_t stream)
{
    const float* x      = (const float*)d_in[0];
    const int*   ei     = (const int*)  d_in[1];
    const int*   batch  = (const int*)  d_in[2];
    const float* Wrel1  = (const float*)d_in[3];
    const float* Wroot1 = (const float*)d_in[4];
    const float* b1     = (const float*)d_in[5];
    const float* bn1_g  = (const float*)d_in[6];
    const float* bn1_b  = (const float*)d_in[7];
    const float* bn1_m  = (const float*)d_in[8];
    const float* bn1_v  = (const float*)d_in[9];
    const float* Wrel2  = (const float*)d_in[10];
    const float* Wroot2 = (const float*)d_in[11];
    const float* b2     = (const float*)d_in[12];
    const float* bn2_g  = (const float*)d_in[13];
    const float* bn2_b  = (const float*)d_in[14];
    const float* bn2_m  = (const float*)d_in[15];
    const float* bn2_v  = (const float*)d_in[16];
    const float* W_lin1 = (const float*)d_in[17];
    const float* b_lin1 = (const float*)d_in[18];
    const float* W_lin2 = (const float*)d_in[19];
    const float* b_lin2 = (const float*)d_in[20];
    float* out = (float*)d_out;

    int n = in_sizes[0] / NFEAT;     // 100000
    int E = in_sizes[1] / 2;         // 3200000
    int G = out_size;                // 512
    int nbuck = (n + BW - 1) / BW;   // 196 buckets of 512 nodes (must be <= 256)
    int neb = (E + EPB - 1) / EPB;   // 391 edge blocks
    int qs = (n + 3) >> 2;           // src quartile size

    char* p = (char*)d_ws;
    float* y1   = (float*)p;  p += (size_t)n * F1P * 4;       // 12.8 MB
    float* r1   = (float*)p;  p += (size_t)n * F1P * 4;       // 12.8 MB
    float* y2   = (float*)p;  p += (size_t)n * F2 * 4;        // 8 MB
    float* r2   = (float*)p;  p += (size_t)n * F2 * 4;        // 8 MB
    int*   ebuf = (int*)p;    p += (size_t)E * 4;             // 12.8 MB
    int*   perm = (int*)p;    p += (size_t)E * 4;             // 12.8 MB
    int* deg      = (int*)p;  p += (size_t)n * 4;             // 0.4 MB
    int* rowstart = (int*)p;  p += (size_t)n * 4;             // 0.4 MB
    int* blockCnt    = (int*)p;  p += (size_t)neb * nbuck * 4;   // 306 KB
    int* blockOff    = (int*)p;  p += (size_t)neb * nbuck * 4;   // 306 KB
    int* bucketTot   = (int*)p;  p += (size_t)nbuck * 4;
    int* bucketStart = (int*)p;  p += (size_t)(nbuck + 1) * 4;
    unsigned* gmaxU = (unsigned*)p;  p += (size_t)G * F2 * 4;
    float*    gsum  = (float*)p;     p += (size_t)G * F2 * 4;
    int*      cnt   = (int*)p;       p += (size_t)G * 4;
    float* Wp       = (float*)p;     p += 2 * 128 * 32 * 4;      // 32 KB
    // total ~69 MB, no overlaps

    (void)hipMemsetAsync(gmaxU, 0, (size_t)G * (F2 * 4 * 2 + 4), stream); // gmaxU+gsum+cnt

    // --- bucket sort (no global atomics); p1 also preps Wp, p4 folds p3 ---
    k_p1<<<neb + 1, 512, 0, stream>>>(ei, blockCnt, E, nbuck, Wrel1, Wroot1, Wp, neb);
    k_p2<<<nbuck, 256, 0, stream>>>(blockCnt, blockOff, bucketTot, neb, nbuck);
    k_p4<<<neb, 512, 0, stream>>>(ei, bucketTot, blockOff, ebuf, bucketStart, E, nbuck);
    k_p6<<<nbuck * 2, 512, 0, stream>>>(ebuf, bucketStart, perm, deg, rowstart, n,
                                        qs, 2 * qs, 3 * qs);

    // --- projections + fused aggregations ---
    k_proj1<<<(n + 63) / 64, 512, 0, stream>>>(x, Wp, y1, r1, n);
    k_agg1m<<<(n + 31) / 32, 256, 0, stream>>>(rowstart, deg, perm, y1, r1,
                                               b1, bn1_g, bn1_b, bn1_m, bn1_v,
                                               Wrel2, Wroot2, b2, y2, r2, n);
    k_agg2p<<<(n + 31) / 32, 256, 0, stream>>>(rowstart, deg, perm, y2, r2, batch,
                                               bn2_g, bn2_b, bn2_m, bn2_v,
                                               gmaxU, gsum, cnt, n);
    k_head<<<(G + 255) / 256, 256, 0, stream>>>(gmaxU, gsum, cnt, W_lin1, b_lin1,
                                                W_lin2, b_lin2, out, G);
}

// Round 15
// 360.098 us; speedup vs baseline: 1.2341x; 1.2341x over previous
//
#include <hip/hip_runtime.h>
#include <math.h>

#define NFEAT 128
#define F1    30   // conv1 out features
#define F1P   32   // padded width for conv1 tables
#define F2    20   // conv2 out features

#define EPB   8192   // edges per block in CSR-build passes
#define BW    512    // bucket width (nodes per bucket), key = dst >> 9
#define EDCAP 9216   // LDS staging cap per half-bucket (mean 8192 + 11 sigma)

// ------- k_p1: per-block bucket histogram; last block preps padded weights -----
__global__ __launch_bounds__(512) void k_p1(
    const int* __restrict__ ei, int* __restrict__ blockCnt, int E, int nbuck,
    const float* __restrict__ Wrel, const float* __restrict__ Wroot,
    float* __restrict__ Wp, int neb)
{
    int t = threadIdx.x;
    if (blockIdx.x == (unsigned)neb) {            // fused k_prepw
        for (int i = t; i < 2 * 128 * 32; i += 512) {
            int table = i >> 12, rem = i & 4095, k = rem >> 5, j = rem & 31;
            const float* W = table ? Wroot : Wrel;
            Wp[i] = (j < F1) ? W[k * F1 + j] : 0.f;
        }
        return;
    }
    __shared__ int lh[256];
    for (int i = t; i < 256; i += 512) lh[i] = 0;
    __syncthreads();
    const int* dst = ei + E;
    int base = blockIdx.x * EPB;
#pragma unroll 4
    for (int k = 0; k < EPB / 512; k++) {
        int e = base + k * 512 + t;
        if (e < E) atomicAdd(&lh[dst[e] >> 9], 1);
    }
    __syncthreads();
    int* out = blockCnt + (size_t)blockIdx.x * nbuck;
    for (int i = t; i < nbuck; i += 512) out[i] = lh[i];
}

// ------- k_p2: per-bucket exclusive scan across edge-blocks --------------------
__global__ __launch_bounds__(256) void k_p2(
    const int* __restrict__ blockCnt, int* __restrict__ blockOff,
    int* __restrict__ bucketTot, int neb, int nbuck)
{
    __shared__ int sdata[256];
    __shared__ int carry_s;
    int b = blockIdx.x;
    int t = threadIdx.x;
    if (t == 0) carry_s = 0;
    __syncthreads();
    for (int base = 0; base < neb; base += 512) {
        int i0 = base + 2 * t, i1 = i0 + 1;
        int c0 = (i0 < neb) ? blockCnt[(size_t)i0 * nbuck + b] : 0;
        int c1 = (i1 < neb) ? blockCnt[(size_t)i1 * nbuck + b] : 0;
        int s = c0 + c1;
        sdata[t] = s;
        __syncthreads();
        for (int off = 1; off < 256; off <<= 1) {
            int tmp = (t >= off) ? sdata[t - off] : 0;
            __syncthreads();
            sdata[t] += tmp;
            __syncthreads();
        }
        int ex = carry_s + sdata[t] - s;
        if (i0 < neb) blockOff[(size_t)i0 * nbuck + b] = ex;
        if (i1 < neb) blockOff[(size_t)i1 * nbuck + b] = ex + c0;
        __syncthreads();
        if (t == 255) carry_s += sdata[255];
        __syncthreads();
    }
    if (t == 0) bucketTot[b] = carry_s;
}

// ------- k_p4: folds p3 (per-block scan of bucketTot) + bucket scatter ---------
__global__ __launch_bounds__(512) void k_p4(
    const int* __restrict__ ei, const int* __restrict__ bucketTot,
    const int* __restrict__ blockOff, int* __restrict__ ebuf,
    int* __restrict__ gBucketStart, int E, int nbuck)
{
    __shared__ int sV[256];       // bucketTot values
    __shared__ int sS[256];       // inclusive scan
    __shared__ int cur[256];
    int t = threadIdx.x;
    if (t < 256) {
        int v = (t < nbuck) ? bucketTot[t] : 0;
        sV[t] = v;
        sS[t] = v;
    }
    __syncthreads();
    for (int off = 1; off < 256; off <<= 1) {
        int tmp = 0;
        if (t < 256 && t >= off) tmp = sS[t - off];
        __syncthreads();
        if (t < 256) sS[t] += tmp;
        __syncthreads();
    }
    // bucketStart[i] = incl[i] - v[i]  (exclusive)
    const int* boff = blockOff + (size_t)blockIdx.x * nbuck;
    if (t < 256) {
        int bs = sS[t] - sV[t];
        cur[t] = (t < nbuck) ? bs + boff[t] : 0;
        if (blockIdx.x == 0) {                    // publish for k_p6
            if (t < nbuck) gBucketStart[t] = bs;
            if (t == 0) gBucketStart[nbuck] = sS[255];
        }
    }
    __syncthreads();
    const int* dst = ei + E;
    int base = blockIdx.x * EPB;
#pragma unroll 4
    for (int k = 0; k < EPB / 512; k++) {
        int e = base + k * 512 + t;
        if (e < E) {
            int s = ei[e], d = dst[e];
            int p = atomicAdd(&cur[d >> 9], 1);
            ebuf[p] = (s << 9) | (d & 511);
        }
    }
}

// p6: per-HALF-bucket LDS counting sort -> perm (sequential write) + deg/rowstart
__global__ __launch_bounds__(512) void k_p6(
    const int* __restrict__ ebuf, const int* __restrict__ bucketStart,
    int* __restrict__ perm, int* __restrict__ deg, int* __restrict__ rowstart,
    int n, int t1, int t2, int t3)
{
    __shared__ int ed2[EDCAP];            // 36 KB staging
    __shared__ int hist[1024];            // (node-in-half, quartile) bins
    __shared__ int sdata[512];
    __shared__ int m0_s;
    int t = threadIdx.x;
    int b = blockIdx.x >> 1;
    int h = blockIdx.x & 1;
    int lo = bucketStart[b], hi = bucketStart[b + 1];
    hist[t] = 0; hist[t + 512] = 0;
    if (t == 0) m0_s = 0;
    __syncthreads();

    int c0 = 0;
    for (int p = lo + t; p < hi; p += 512) {
        int e = ebuf[p];
        int dl9 = e & 511;
        if ((dl9 >> 8) == 0) c0++;
        if ((dl9 >> 8) == h) {
            int src = e >> 9;
            int qq = (src >= t1) + (src >= t2) + (src >= t3);
            atomicAdd(&hist[(dl9 & 255) * 4 + qq], 1);
        }
    }
    atomicAdd(&m0_s, c0);
    __syncthreads();

    int v0 = hist[2 * t], v1 = hist[2 * t + 1];
    int ps = v0 + v1;
    sdata[t] = ps;
    __syncthreads();
    for (int off = 1; off < 512; off <<= 1) {
        int tmp = (t >= off) ? sdata[t - off] : 0;
        __syncthreads();
        sdata[t] += tmp;
        __syncthreads();
    }
    int ex = sdata[t] - ps;
    hist[2 * t] = ex;
    hist[2 * t + 1] = ex + v0;
    __syncthreads();
    int mh = sdata[511];
    int base = lo + (h ? m0_s : 0);

    if (t < 256) {
        int node = b * BW + h * 256 + t;
        if (node < n) {
            int s0 = hist[t * 4];
            int s1 = (t == 255) ? mh : hist[(t + 1) * 4];
            deg[node] = s1 - s0;
            rowstart[node] = base + s0;
        }
    }
    __syncthreads();

    for (int p = lo + t; p < hi; p += 512) {
        int e = ebuf[p];
        int dl9 = e & 511;
        if ((dl9 >> 8) == h) {
            int src = e >> 9;
            int qq = (src >= t1) + (src >= t2) + (src >= t3);
            int pos = atomicAdd(&hist[(dl9 & 255) * 4 + qq], 1);
            if (pos < EDCAP) ed2[pos] = src;
            else perm[base + pos] = src;
        }
    }
    __syncthreads();

    int mw = min(mh, EDCAP);
    for (int i = t; i < mw; i += 512) perm[base + i] = ed2[i];
}

// ------- k_proj1: block=512 (8 waves), 64 nodes/block. wave=(table,q) uniform ---
__global__ __launch_bounds__(512) void k_proj1(
    const float* __restrict__ x, const float* __restrict__ Wp,
    float* __restrict__ y1, float* __restrict__ r1, int n)
{
    __shared__ float4 xs4[2048];           // 64 rows x 32 k4, swizzled, 32 KB
    int tid = threadIdx.x;
    int base = blockIdx.x * 64;

#pragma unroll
    for (int it = 0; it < 4; it++) {
        int idx = it * 512 + tid;
        int k4 = idx & 31, row = idx >> 5;
        int gnode = base + row;
        float4 v = make_float4(0.f, 0.f, 0.f, 0.f);
        if (gnode < n) v = ((const float4*)(x + (size_t)gnode * NFEAT))[k4];
        xs4[k4 * 64 + (row ^ k4)] = v;
    }
    __syncthreads();

    int lane = tid & 63;
    int combo = __builtin_amdgcn_readfirstlane(tid >> 6);  // 0..7, wave-uniform
    int table = combo >> 2, q = combo & 3;
    int node = base + lane;
    if (node >= n) return;

    const float* Wt = Wp + table * 4096 + q * 8;           // SGPR-derived
    float acc[8];
#pragma unroll
    for (int j = 0; j < 8; j++) acc[j] = 0.f;

    for (int k4 = 0; k4 < 32; k4++) {
        float4 xk = xs4[k4 * 64 + (lane ^ k4)];
#pragma unroll
        for (int kk = 0; kk < 4; kk++) {
            float xs = kk == 0 ? xk.x : kk == 1 ? xk.y : kk == 2 ? xk.z : xk.w;
            const float* w = Wt + (k4 * 4 + kk) * 32;      // wave-uniform -> s_load
            acc[0] += xs * w[0]; acc[1] += xs * w[1];
            acc[2] += xs * w[2]; acc[3] += xs * w[3];
            acc[4] += xs * w[4]; acc[5] += xs * w[5];
            acc[6] += xs * w[6]; acc[7] += xs * w[7];
        }
    }
    float* outp = (table ? r1 : y1) + (size_t)node * F1P + q * 8;
    ((float4*)outp)[0] = make_float4(acc[0], acc[1], acc[2], acc[3]);
    ((float4*)outp)[1] = make_float4(acc[4], acc[5], acc[6], acc[7]);
}

// ------- k_agg1m: conv1 gather + bn1 + 30->20x2 matmul fused (32 nodes/block) --
__global__ __launch_bounds__(256) void k_agg1m(
    const int* __restrict__ rowstart, const int* __restrict__ deg,
    const int* __restrict__ perm, const float* __restrict__ y1,
    const float* __restrict__ r1,
    const float* __restrict__ b1, const float* __restrict__ g1,
    const float* __restrict__ bb1, const float* __restrict__ m1,
    const float* __restrict__ v1,
    const float* __restrict__ Wrel2, const float* __restrict__ Wroot2,
    const float* __restrict__ b2,
    float* __restrict__ y2, float* __restrict__ r2, int n)
{
    __shared__ float sAcc[32][33];
    __shared__ float sH[32][31];
    __shared__ float sW[30][40];        // [k][o]: o<20 -> Wrel2, o>=20 -> Wroot2
    __shared__ float sP[4][30];         // b1, sc1, m1, bb1
    __shared__ float sB2[20];
    int t = threadIdx.x;
    int base = blockIdx.x * 32;
    int nl = t >> 3, q = t & 7;
    int node = base + nl;

    if (t < 30) {
        sP[0][t] = b1[t];
        sP[1][t] = g1[t] / sqrtf(v1[t] + 1e-5f);
        sP[2][t] = m1[t];
        sP[3][t] = bb1[t];
    }
    if (t >= 32 && t < 52) sB2[t - 32] = b2[t - 32];
    for (int i = t; i < 1200; i += 256) {
        int k = i / 40, o = i - k * 40;
        sW[k][o] = (o < 20) ? Wrel2[k * 20 + o] : Wroot2[k * 20 + (o - 20)];
    }

    // gather (same order as before -> identical sums)
    float4 acc = {0.f, 0.f, 0.f, 0.f};
    if (node < n) {
        int s = rowstart[node], e = s + deg[node];
        int j = s;
        for (; j + 8 <= e; j += 8) {
            int myp = perm[j + q];
#pragma unroll
            for (int k = 0; k < 8; k++) {
                int sr = __shfl(myp, k, 8);
                float4 v = *(const float4*)(y1 + (size_t)sr * F1P + q * 4);
                acc.x += v.x; acc.y += v.y; acc.z += v.z; acc.w += v.w;
            }
        }
        for (; j < e; j++) {
            int sr = perm[j];
            float4 v = *(const float4*)(y1 + (size_t)sr * F1P + q * 4);
            acc.x += v.x; acc.y += v.y; acc.z += v.z; acc.w += v.w;
        }
    }
    sAcc[nl][q * 4 + 0] = acc.x; sAcc[nl][q * 4 + 1] = acc.y;
    sAcc[nl][q * 4 + 2] = acc.z; sAcc[nl][q * 4 + 3] = acc.w;
    __syncthreads();

    // h = bn1(relu(acc + r1 + b1)) over 32x30, coalesced r1 reads
    for (int w = t; w < 960; w += 256) {
        int wl = w / 30, k = w - wl * 30;
        int nd = base + wl;
        if (nd < n) {
            float a = sAcc[wl][k] + r1[(size_t)nd * F1P + k] + sP[0][k];
            a = fmaxf(a, 0.f);
            sH[wl][k] = (a - sP[2][k]) * sP[1][k] + sP[3][k];
        }
    }
    __syncthreads();

    // matmul: thread (nl,q) computes 5 outputs; o<20 -> y2, o>=20 -> r2 (+b2)
    if (node < n) {
        int ob = q * 5;
        bool isroot = (ob >= 20);
        float o0 = 0.f, o1 = 0.f, o2 = 0.f, o3 = 0.f, o4 = 0.f;
        if (isroot) {
            o0 = sB2[ob - 20]; o1 = sB2[ob - 19]; o2 = sB2[ob - 18];
            o3 = sB2[ob - 17]; o4 = sB2[ob - 16];
        }
        for (int k = 0; k < 30; k++) {
            float hk = sH[nl][k];
            o0 += hk * sW[k][ob + 0];
            o1 += hk * sW[k][ob + 1];
            o2 += hk * sW[k][ob + 2];
            o3 += hk * sW[k][ob + 3];
            o4 += hk * sW[k][ob + 4];
        }
        float* dst = isroot ? (r2 + (size_t)node * F2 + (ob - 20))
                            : (y2 + (size_t)node * F2 + ob);
        dst[0] = o0; dst[1] = o1; dst[2] = o2; dst[3] = o3; dst[4] = o4;
    }
}

// ------- k_agg2p: conv2 gather + bn2 + pool flush fused (32 nodes/block) -------
__global__ __launch_bounds__(256) void k_agg2p(
    const int* __restrict__ rowstart, const int* __restrict__ deg,
    const int* __restrict__ perm, const float* __restrict__ y2,
    const float* __restrict__ r2, const int* __restrict__ batch,
    const float* __restrict__ g2, const float* __restrict__ bb2,
    const float* __restrict__ m2, const float* __restrict__ v2,
    unsigned* __restrict__ gmaxU, float* __restrict__ gsum,
    int* __restrict__ cnt, int n)
{
    __shared__ float sAcc[32][21];
    __shared__ float sH[32][21];
    __shared__ float sSc[20], sM[20], sBb[20];
    __shared__ int   sB[32];
    int t = threadIdx.x;
    int base = blockIdx.x * 32;
    int nl = t >> 3, q = t & 7;
    int node = base + nl;

    if (t < 20) {
        sSc[t] = g2[t] / sqrtf(v2[t] + 1e-5f);
        sM[t]  = m2[t];
    }
    if (t >= 32 && t < 52) sBb[t - 32] = bb2[t - 32];
    if (t >= 64 && t < 96) {
        int nd = base + (t - 64);
        sB[t - 64] = (nd < n) ? batch[nd] : -1;
    }

    bool valid = (q < 5);
    float4 acc = {0.f, 0.f, 0.f, 0.f};
    if (node < n) {
        int s = rowstart[node], e = s + deg[node];
        int j = s;
        for (; j + 8 <= e; j += 8) {
            int myp = perm[j + q];
#pragma unroll
            for (int k = 0; k < 8; k++) {
                int sr = __shfl(myp, k, 8);
                if (valid) {
                    float4 v = *(const float4*)(y2 + (size_t)sr * F2 + q * 4);
                    acc.x += v.x; acc.y += v.y; acc.z += v.z; acc.w += v.w;
                }
            }
        }
        if (valid) {
            for (; j < e; j++) {
                int sr = perm[j];
                float4 v = *(const float4*)(y2 + (size_t)sr * F2 + q * 4);
                acc.x += v.x; acc.y += v.y; acc.z += v.z; acc.w += v.w;
            }
        }
    }
    if (valid && node < n) {
        sAcc[nl][q * 4 + 0] = acc.x; sAcc[nl][q * 4 + 1] = acc.y;
        sAcc[nl][q * 4 + 2] = acc.z; sAcc[nl][q * 4 + 3] = acc.w;
    }
    __syncthreads();

    // h2 = bn2(relu(acc + r2)), r2 reads coalesced (b2 already folded into r2)
    for (int w = t; w < 640; w += 256) {
        int wl = w / 20, f = w - wl * 20;
        int nd = base + wl;
        if (nd < n) {
            float a = sAcc[wl][f] + r2[(size_t)nd * F2 + f];
            a = fmaxf(a, 0.f);
            sH[wl][f] = (a - sM[f]) * sSc[f] + sBb[f];
        }
    }
    __syncthreads();

    // segmented flush (batch sorted): t<20 per-feature sum/max, t==20 counts
    if (t < 20) {
        int f = t;
        int curg = -1; float sm = 0.f, mx = -3.4e38f;
        for (int wl = 0; wl < 32; wl++) {
            int g = sB[wl];
            if (g < 0) break;
            if (g != curg) {
                if (curg >= 0) {
                    atomicAdd(&gsum[curg * F2 + f], sm);
                    unsigned bits = __float_as_uint(mx);
                    unsigned mp = (bits & 0x80000000u) ? ~bits : (bits | 0x80000000u);
                    atomicMax(&gmaxU[curg * F2 + f], mp);
                }
                curg = g; sm = 0.f; mx = -3.4e38f;
            }
            float h2 = sH[wl][f];
            sm += h2; mx = fmaxf(mx, h2);
        }
        if (curg >= 0) {
            atomicAdd(&gsum[curg * F2 + f], sm);
            unsigned bits = __float_as_uint(mx);
            unsigned mp = (bits & 0x80000000u) ? ~bits : (bits | 0x80000000u);
            atomicMax(&gmaxU[curg * F2 + f], mp);
        }
    } else if (t == 20) {
        int curg = -1, c = 0;
        for (int wl = 0; wl < 32; wl++) {
            int g = sB[wl];
            if (g < 0) break;
            if (g != curg) {
                if (curg >= 0) atomicAdd(&cnt[curg], c);
                curg = g; c = 0;
            }
            c++;
        }
        if (curg >= 0) atomicAdd(&cnt[curg], c);
    }
}

// ---------------- Kernel F: head MLP + sigmoid ---------------------------------
__global__ __launch_bounds__(256) void k_head(
    const unsigned* __restrict__ gmaxU, const float* __restrict__ gsum,
    const int* __restrict__ cnt,
    const float* __restrict__ W1, const float* __restrict__ b1h,
    const float* __restrict__ W2, const float* __restrict__ b2h,
    float* __restrict__ out, int G)
{
    int g = blockIdx.x * 256 + threadIdx.x;
    if (g >= G) return;
    int c = cnt[g];
    float cf = fmaxf((float)c, 1.f);
    float z[2 * F2];
#pragma unroll
    for (int j = 0; j < F2; j++) {
        unsigned u = gmaxU[g * F2 + j];
        float gm = 0.f;
        if (c != 0) {
            gm = (u & 0x80000000u) ? __uint_as_float(u & 0x7FFFFFFFu)
                                   : __uint_as_float(~u);
            if (!isfinite(gm)) gm = 0.f;
        }
        z[j]      = gm;
        z[F2 + j] = gsum[g * F2 + j] / cf;
    }
    float a[10];
#pragma unroll
    for (int i = 0; i < 10; i++) a[i] = b1h[i];
    for (int k = 0; k < 2 * F2; k++) {
        float zk = z[k];
#pragma unroll
        for (int i = 0; i < 10; i++) a[i] += zk * W1[k * 10 + i];
    }
    float o = b2h[0];
#pragma unroll
    for (int i = 0; i < 10; i++) o += fmaxf(a[i], 0.f) * W2[i];
    out[g] = 1.f / (1.f + expf(-o));
}

// ---------------- launch (dedicated regions, NO aliasing) -----------------------
extern "C" void kernel_launch(void* const* d_in, const int* in_sizes, int n_in,
                              void* d_out, int out_size, void* d_ws, size_t ws_size,
                              hipStream_t stream)
{
    const float* x      = (const float*)d_in[0];
    const int*   ei     = (const int*)  d_in[1];
    const int*   batch  = (const int*)  d_in[2];
    const float* Wrel1  = (const float*)d_in[3];
    const float* Wroot1 = (const float*)d_in[4];
    const float* b1     = (const float*)d_in[5];
    const float* bn1_g  = (const float*)d_in[6];
    const float* bn1_b  = (const float*)d_in[7];
    const float* bn1_m  = (const float*)d_in[8];
    const float* bn1_v  = (const float*)d_in[9];
    const float* Wrel2  = (const float*)d_in[10];
    const float* Wroot2 = (const float*)d_in[11];
    const float* b2     = (const float*)d_in[12];
    const float* bn2_g  = (const float*)d_in[13];
    const float* bn2_b  = (const float*)d_in[14];
    const float* bn2_m  = (const float*)d_in[15];
    const float* bn2_v  = (const float*)d_in[16];
    const float* W_lin1 = (const float*)d_in[17];
    const float* b_lin1 = (const float*)d_in[18];
    const float* W_lin2 = (const float*)d_in[19];
    const float* b_lin2 = (const float*)d_in[20];
    float* out = (float*)d_out;

    int n = in_sizes[0] / NFEAT;     // 100000
    int E = in_sizes[1] / 2;         // 3200000
    int G = out_size;                // 512
    int nbuck = (n + BW - 1) / BW;   // 196 buckets of 512 nodes (must be <= 256)
    int neb = (E + EPB - 1) / EPB;   // 391 edge blocks
    int qs = (n + 3) >> 2;           // src quartile size

    char* p = (char*)d_ws;
    float* y1   = (float*)p;  p += (size_t)n * F1P * 4;       // 12.8 MB
    float* r1   = (float*)p;  p += (size_t)n * F1P * 4;       // 12.8 MB
    float* y2   = (float*)p;  p += (size_t)n * F2 * 4;        // 8 MB
    float* r2   = (float*)p;  p += (size_t)n * F2 * 4;        // 8 MB
    int*   ebuf = (int*)p;    p += (size_t)E * 4;             // 12.8 MB
    int*   perm = (int*)p;    p += (size_t)E * 4;             // 12.8 MB
    int* deg      = (int*)p;  p += (size_t)n * 4;             // 0.4 MB
    int* rowstart = (int*)p;  p += (size_t)n * 4;             // 0.4 MB
    int* blockCnt    = (int*)p;  p += (size_t)neb * nbuck * 4;   // 306 KB
    int* blockOff    = (int*)p;  p += (size_t)neb * nbuck * 4;   // 306 KB
    int* bucketTot   = (int*)p;  p += (size_t)nbuck * 4;
    int* bucketStart = (int*)p;  p += (size_t)(nbuck + 1) * 4;
    unsigned* gmaxU = (unsigned*)p;  p += (size_t)G * F2 * 4;
    float*    gsum  = (float*)p;     p += (size_t)G * F2 * 4;
    int*      cnt   = (int*)p;       p += (size_t)G * 4;
    float* Wp       = (float*)p;     p += 2 * 128 * 32 * 4;      // 32 KB
    // total ~69 MB, no overlaps

    (void)hipMemsetAsync(gmaxU, 0, (size_t)G * (F2 * 4 * 2 + 4), stream); // gmaxU+gsum+cnt

    // --- bucket sort (no global atomics); p1 also preps Wp, p4 folds p3 ---
    k_p1<<<neb + 1, 512, 0, stream>>>(ei, blockCnt, E, nbuck, Wrel1, Wroot1, Wp, neb);
    k_p2<<<nbuck, 256, 0, stream>>>(blockCnt, blockOff, bucketTot, neb, nbuck);
    k_p4<<<neb, 512, 0, stream>>>(ei, bucketTot, blockOff, ebuf, bucketStart, E, nbuck);
    k_p6<<<nbuck * 2, 512, 0, stream>>>(ebuf, bucketStart, perm, deg, rowstart, n,
                                        qs, 2 * qs, 3 * qs);

    // --- projections + fused aggregations ---
    k_proj1<<<(n + 63) / 64, 512, 0, stream>>>(x, Wp, y1, r1, n);
    k_agg1m<<<(n + 31) / 32, 256, 0, stream>>>(rowstart, deg, perm, y1, r1,
                                               b1, bn1_g, bn1_b, bn1_m, bn1_v,
                                               Wrel2, Wroot2, b2, y2, r2, n);
    k_agg2p<<<(n + 31) / 32, 256, 0, stream>>>(rowstart, deg, perm, y2, r2, batch,
                                               bn2_g, bn2_b, bn2_m, bn2_v,
                                               gmaxU, gsum, cnt, n);
    k_head<<<(G + 255) / 256, 256, 0, stream>>>(gmaxU, gsum, cnt, W_lin1, b_lin1,
                                                W_lin2, b_lin2, out, G);
}